// Round 9
// baseline (91.250 us; speedup 1.0000x reference)
//
#include <hip/hip_runtime.h>
#include <math.h>

#define G_ 320
#define N_ 1000
#define T_ 10
#define C_ 96
#define E_ 8000
#define NSLICE 8        // node slices per graph (one wave each)
#define NS 125          // nodes per slice
#define CAP2 1500       // slot capacity per slice (mean ~1125, +12 sigma)
#define CCAP 320        // per-chunk LDS slot buffer (mean ~144, +15 sigma)
#define CHN 16          // nodes per chunk
#define NCH 8           // chunks per slice (last = 13 nodes)

// ws layout (bytes):
//     0: P      96 float4   (wl, wr, bl+br, 0.4*att)
//  1536: lin3   3 f
//  1552: offsG  8*126 i     (per-slice LOCAL CSR offsets)
//  5584: slots  8*CAP2 int2 (per-slice packed (src,dst), global node ids)

// ---------------- kA: shared CSR build, one block per slice ----------------
__global__ __launch_bounds__(512) void kA(
        const int* __restrict__ ei,
        const float* __restrict__ Wl, const float* __restrict__ bl,
        const float* __restrict__ Wr, const float* __restrict__ br,
        const float* __restrict__ att,
        float4* __restrict__ P, float* __restrict__ lin3g,
        int* __restrict__ offsG, int2* __restrict__ slots) {
    __shared__ int cnt[128], cur[128], offsL[130];
    const int tid = threadIdx.x;
    const int q = blockIdx.x;           // slice 0..7
    const int lo = q * NS;

    if (q == 0) {   // pack channel params + lin3 (block 0 only)
        if (tid < C_)
            P[tid] = make_float4(Wl[tid], Wr[tid], bl[tid] + br[tid], 0.4f * att[tid]);
        int w = tid >> 6, lane = tid & 63;
        if (w < 3) {
            float s = 0.f;
            for (int i = lane; i < C_; i += 64) {
                float a = att[i];
                float m = (w == 0) ? Wl[i] : (w == 1) ? Wr[i] : (bl[i] + br[i]);
                s += a * m;
            }
            for (int off = 32; off; off >>= 1) s += __shfl_down(s, off);
            if (lane == 0) lin3g[w] = 0.6f * s;
        }
    }
    for (int i = tid; i < 128; i += 512) cnt[i] = (i < NS) ? 1 : 0;  // self-loop
    __syncthreads();

    const int4* d4 = (const int4*)(ei + E_);
    const int4* s4 = (const int4*)ei;
    for (int j = tid; j < E_ / 4; j += 512) {
        int4 d = d4[j];
        int r0 = d.x - lo, r1 = d.y - lo, r2 = d.z - lo, r3 = d.w - lo;
        if ((unsigned)r0 < (unsigned)NS) atomicAdd(&cnt[r0], 1);
        if ((unsigned)r1 < (unsigned)NS) atomicAdd(&cnt[r1], 1);
        if ((unsigned)r2 < (unsigned)NS) atomicAdd(&cnt[r2], 1);
        if ((unsigned)r3 < (unsigned)NS) atomicAdd(&cnt[r3], 1);
    }
    __syncthreads();

    if (tid < 64) {   // wave-0 shuffle scan, lane owns 2 counters
        int b2 = tid * 2;
        int a0 = cnt[b2], a1 = cnt[b2 + 1];
        int s = a0 + a1;
        int pre = s;
        for (int off = 1; off < 64; off <<= 1) {
            int tv = __shfl_up(pre, off);
            if (tid >= off) pre += tv;
        }
        int base = pre - s;
        offsL[b2] = base;          cur[b2] = base;
        offsL[b2 + 1] = base + a0; cur[b2 + 1] = base + a0;
    }
    __syncthreads();

    int2* sl = slots + (size_t)q * CAP2;
    for (int j = tid; j < E_ / 4; j += 512) {
        int4 d = d4[j];
        int4 s = s4[j];
#define SCAT(DD, SS) { int r = (DD) - lo;                                    \
        if ((unsigned)r < (unsigned)NS) {                                    \
            int pos = atomicAdd(&cur[r], 1);                                 \
            sl[pos] = make_int2((SS), (DD)); } }
        SCAT(d.x, s.x) SCAT(d.y, s.y) SCAT(d.z, s.z) SCAT(d.w, s.w)
#undef SCAT
    }
    for (int i = tid; i < NS; i += 512) {       // self-loops
        int pos = atomicAdd(&cur[i], 1);
        sl[pos] = make_int2(lo + i, lo + i);
    }
    for (int i = tid; i <= NS; i += 512) offsG[q * (NS + 1) + i] = offsL[i];
}

// ---- kF: wave-autonomous chunked logits+softmax+expand, no main-loop barriers ----
// block = 128 thr = 2 waves; wave owns slice (blockIdx.x*2 + wave) of graph blockIdx.y.
__global__ __launch_bounds__(128, 4) void kF(
        const float* __restrict__ x, const float4* __restrict__ P,
        const float* __restrict__ lin3g, const int* __restrict__ offsG,
        const int2* __restrict__ slots,
        const float* __restrict__ Wl, const float* __restrict__ bl,
        const float* __restrict__ bias, float4* __restrict__ out) {
    __shared__ float xgs[N_];
    __shared__ float Lb[2][CCAP];
    __shared__ float Ub[2][CCAP];
    __shared__ int offsW[2][NS + 1];
    __shared__ float Sch[2][CHN];
    __shared__ float4 wl4s[C_ / 4], cb4s[C_ / 4];

    const int tid = threadIdx.x;
    const int w = tid >> 6, lane = tid & 63;
    const int qh = blockIdx.x, g = blockIdx.y;
    const int slice = qh * 2 + w;
    const int lo = slice * NS;
    const int t = g % T_;

    const float* xg = x + g * N_;
    for (int i = tid; i < N_ / 4; i += 128)
        ((float4*)xgs)[i] = ((const float4*)xg)[i];
    if (tid < C_) {   // expansion tables (wl, combined bias+pos)
        int k2 = tid & ~1;
        float dt = __expf(-(float)k2 * (logf(10000.0f) / (float)C_));
        float ang = (float)t * dt;
        float pe = (tid & 1) ? cosf(ang) : sinf(ang);
        ((float*)wl4s)[tid] = Wl[tid];
        ((float*)cb4s)[tid] = bl[tid] + bias[tid] + pe;
    }
    for (int i = lane; i <= NS; i += 64)
        offsW[w][i] = offsG[slice * (NS + 1) + i];
    __syncthreads();   // the ONLY block barrier

    const float la = lin3g[0], lb = lin3g[1], lc = lin3g[2];
    const int2* sl = slots + (size_t)slice * CAP2;

    for (int ch = 0; ch < NCH; ++ch) {
        const int n0 = ch * CHN;
        const int nch = (NS - n0 < CHN) ? (NS - n0) : CHN;
        const int s0 = offsW[w][n0];
        const int s1 = offsW[w][n0 + nch];

        // gather + logits for this chunk's slots (ILP 2)
        for (int p = s0 + lane; p < s1; p += 128) {
            int p1 = p + 64;
            bool ok1 = p1 < s1;
            int2 sd0 = sl[p];
            int2 sd1 = sl[ok1 ? p1 : p];
            float u0 = xgs[sd0.x], v0 = xgs[sd0.y];
            float u1 = xgs[sd1.x], v1 = xgs[sd1.y];
            float a0 = 0.f, a1 = 0.f;
#pragma unroll 8
            for (int c = 0; c < C_; c++) {
                float4 qv = P[c];                 // uniform -> s_load path
                float w0 = fmaf(u0, qv.x, fmaf(v0, qv.y, qv.z));
                float w1 = fmaf(u1, qv.x, fmaf(v1, qv.y, qv.z));
                a0 = fmaf(qv.w, fabsf(w0), a0);
                a1 = fmaf(qv.w, fabsf(w1), a1);
            }
            Lb[w][p - s0] = fmaf(u0, la, fmaf(v0, lb, lc)) + a0;
            Ub[w][p - s0] = u0;
            if (ok1) {
                Lb[w][p1 - s0] = fmaf(u1, la, fmaf(v1, lb, lc)) + a1;
                Ub[w][p1 - s0] = u1;
            }
        }

        // per-node branchless online softmax (lanes 0..nch-1), wave-internal
        if (lane < nch) {
            int a = offsW[w][n0 + lane] - s0;
            int b = offsW[w][n0 + lane + 1] - s0;
            float m = -INFINITY, den = 0.f, num = 0.f;
            for (int p = a; p < b; ++p) {
                float l = Lb[w][p], uu = Ub[w][p];
                float nm = fmaxf(m, l);
                float sc = __expf(m - nm);
                float ex = __expf(l - nm);
                den = den * sc + ex;
                num = fmaf(ex, uu, num * sc);
                m = nm;
            }
            Sch[w][lane] = num / den;
        }

        // write chunk slab (nch x 24 float4, coalesced); incremental i/24
        float4* out4 = out + (size_t)(g * N_ + lo + n0) * (C_ / 4);
        const int tot = nch * (C_ / 4);
        int node = lane / 24, c4 = lane % 24;
        for (int i = lane; i < tot; i += 64) {
            float s = Sch[w][node];
            float4 wv = wl4s[c4], cb = cb4s[c4];
            out4[i] = make_float4(fmaf(s, wv.x, cb.x), fmaf(s, wv.y, cb.y),
                                  fmaf(s, wv.z, cb.z), fmaf(s, wv.w, cb.w));
            int c4n = c4 + 16;                   // 64 = 2*24 + 16
            int carry = (c4n >= 24) ? 1 : 0;
            node += 2 + carry;
            c4 = c4n - (carry ? 24 : 0);
        }
    }
}

extern "C" void kernel_launch(void* const* d_in, const int* in_sizes, int n_in,
                              void* d_out, int out_size, void* d_ws, size_t ws_size,
                              hipStream_t stream) {
    const float* x    = (const float*)d_in[0];
    const int*   ei   = (const int*)d_in[1];
    const float* Wl   = (const float*)d_in[2];
    const float* bl   = (const float*)d_in[3];
    const float* Wr   = (const float*)d_in[4];
    const float* br   = (const float*)d_in[5];
    const float* att  = (const float*)d_in[6];
    const float* bias = (const float*)d_in[7];
    float4* out = (float4*)d_out;

    char* ws = (char*)d_ws;
    float4* P     = (float4*)(ws + 0);
    float*  lin3g = (float*)(ws + 1536);
    int*    offsG = (int*)(ws + 1552);
    int2*   slots = (int2*)(ws + 5584);

    hipLaunchKernelGGL(kA, dim3(NSLICE), dim3(512), 0, stream,
                       ei, Wl, bl, Wr, br, att, P, lin3g, offsG, slots);
    hipLaunchKernelGGL(kF, dim3(NSLICE / 2, G_), dim3(128), 0, stream,
                       x, P, lin3g, offsG, slots, Wl, bl, bias, out);
}

// Round 10
// 57.510 us; speedup vs baseline: 1.5867x; 1.5867x over previous
//
#include <hip/hip_runtime.h>
#include <math.h>

#define G_ 320
#define N_ 1000
#define T_ 10
#define C_ 96
#define E_ 8000
#define QN 250          // nodes per quarter (4 quarters)
#define CAP 2816        // slot capacity per quarter (mean ~2250, >14 sigma)
#define EPT 5           // slots per thread in main logit pass

// ws layout (bytes):
//       0: P      96 float4      (wl, wr, bl+br, 0.4*att)
//    1536: lin3   3 f
//    1552: offsG  4*251 i        (per-quarter LOCAL CSR offsets)
//    5568: slots  4*CAP int2     (per-quarter packed (src,dst))

// ---------------- kA: shared CSR build, one block per quarter ----------------
__global__ __launch_bounds__(512) void kA(
        const int* __restrict__ ei,
        const float* __restrict__ Wl, const float* __restrict__ bl,
        const float* __restrict__ Wr, const float* __restrict__ br,
        const float* __restrict__ att,
        float4* __restrict__ P, float* __restrict__ lin3g,
        int* __restrict__ offsG, int2* __restrict__ slots) {
    __shared__ int cnt[256], cur[256], offsL[260];
    const int tid = threadIdx.x;
    const int q = blockIdx.x;
    const int lo = q * QN;

    if (q == 0) {   // pack channel params + lin3 (block 0 only)
        if (tid < C_)
            P[tid] = make_float4(Wl[tid], Wr[tid], bl[tid] + br[tid], 0.4f * att[tid]);
        int w = tid >> 6, lane = tid & 63;
        if (w < 3) {
            float s = 0.f;
            for (int i = lane; i < C_; i += 64) {
                float a = att[i];
                float m = (w == 0) ? Wl[i] : (w == 1) ? Wr[i] : (bl[i] + br[i]);
                s += a * m;
            }
            for (int off = 32; off; off >>= 1) s += __shfl_down(s, off);
            if (lane == 0) lin3g[w] = 0.6f * s;
        }
    }
    for (int i = tid; i < 256; i += 512) cnt[i] = (i < QN) ? 1 : 0; // self-loop
    __syncthreads();

    const int4* d4 = (const int4*)(ei + E_);
    const int4* s4 = (const int4*)ei;
    for (int j = tid; j < E_ / 4; j += 512) {
        int4 d = d4[j];
        int r0 = d.x - lo, r1 = d.y - lo, r2 = d.z - lo, r3 = d.w - lo;
        if ((unsigned)r0 < (unsigned)QN) atomicAdd(&cnt[r0], 1);
        if ((unsigned)r1 < (unsigned)QN) atomicAdd(&cnt[r1], 1);
        if ((unsigned)r2 < (unsigned)QN) atomicAdd(&cnt[r2], 1);
        if ((unsigned)r3 < (unsigned)QN) atomicAdd(&cnt[r3], 1);
    }
    __syncthreads();

    if (tid < 64) {   // wave-0 shuffle scan, lane owns 4 counters
        int b4 = tid * 4;
        int a0 = cnt[b4], a1 = cnt[b4 + 1], a2 = cnt[b4 + 2], a3 = cnt[b4 + 3];
        int s1 = a0 + a1, s2 = s1 + a2, s3 = s2 + a3;
        int pre = s3;
        for (int off = 1; off < 64; off <<= 1) {
            int tv = __shfl_up(pre, off);
            if (tid >= off) pre += tv;
        }
        int base = pre - s3;
        offsL[b4] = base;          cur[b4] = base;
        offsL[b4 + 1] = base + a0; cur[b4 + 1] = base + a0;
        offsL[b4 + 2] = base + s1; cur[b4 + 2] = base + s1;
        offsL[b4 + 3] = base + s2; cur[b4 + 3] = base + s2;
    }
    __syncthreads();

    int2* sl = slots + (size_t)q * CAP;
    for (int j = tid; j < E_ / 4; j += 512) {
        int4 d = d4[j];
        int4 s = s4[j];
#define SCAT(DD, SS) { int r = (DD) - lo;                                    \
        if ((unsigned)r < (unsigned)QN) {                                    \
            int pos = atomicAdd(&cur[r], 1);                                 \
            sl[pos] = make_int2((SS), (DD)); } }
        SCAT(d.x, s.x) SCAT(d.y, s.y) SCAT(d.z, s.z) SCAT(d.w, s.w)
#undef SCAT
    }
    for (int i = tid; i < QN; i += 512) {       // self-loops
        int pos = atomicAdd(&cur[i], 1);
        sl[pos] = make_int2(lo + i, lo + i);
    }
    for (int i = tid; i <= QN; i += 512) offsG[q * (QN + 1) + i] = offsL[i];
}

// ---- kF2: 2-graph pipelined logits+softmax+expand per (quarter, graph-pair) ----
// write(g0)'s stores drain underneath logits(g1)'s VALU burst.
__global__ __launch_bounds__(512, 4) void kF2(
        const float* __restrict__ x, const float4* __restrict__ P,
        const float* __restrict__ lin3g, const int* __restrict__ offsG,
        const int2* __restrict__ slots,
        const float* __restrict__ Wl, const float* __restrict__ bl,
        const float* __restrict__ bias, float4* __restrict__ out) {
    __shared__ float xgs[2][N_];
    __shared__ float2 LU[CAP];
    __shared__ int offsL[QN + 1];
    __shared__ float Sloc[2][QN];
    __shared__ float4 wl4[C_ / 4];
    __shared__ float4 cb4[2][C_ / 4];

    const int tid = threadIdx.x;
    const int q = blockIdx.x;
    const int g0 = blockIdx.y * 2;
    const int lo = q * QN;

    // stage: both graphs' x (contiguous rows), offsets, expansion tables
    const float4* xg4 = (const float4*)(x + (size_t)g0 * N_);
    for (int i = tid; i < 2 * N_ / 4; i += 512) ((float4*)xgs)[i] = xg4[i];
    for (int i = tid; i <= QN; i += 512) offsL[i] = offsG[q * (QN + 1) + i];
    if (tid < 2 * C_) {
        int it = tid / C_, c = tid % C_;
        int t = (g0 + it) % T_;
        int k2 = c & ~1;
        float dt = __expf(-(float)k2 * (logf(10000.0f) / (float)C_));
        float ang = (float)t * dt;
        float pe = (c & 1) ? cosf(ang) : sinf(ang);
        ((float*)cb4[it])[c] = bl[c] + bias[c] + pe;
    } else if (tid < 3 * C_) {
        int c = tid - 2 * C_;
        ((float*)wl4)[c] = Wl[c];
    }
    __syncthreads();

    const int cntE = offsL[QN];
    const float la = lin3g[0], lb = lin3g[1], lc = lin3g[2];
    const int2* sl = slots + (size_t)q * CAP;

    auto logits = [&](int it) {
        const float* xx = xgs[it];
        float u[EPT], v[EPT], acc[EPT];
#pragma unroll
        for (int k = 0; k < EPT; k++) {
            int p = tid + k * 512;
            int2 sd = sl[p < cntE ? p : 0];
            u[k] = xx[sd.x]; v[k] = xx[sd.y]; acc[k] = 0.f;
        }
#pragma unroll 8
        for (int c = 0; c < C_; c++) {
            float4 qv = P[c];                    // uniform -> s_load path
#pragma unroll
            for (int k = 0; k < EPT; k++) {
                float wv = fmaf(u[k], qv.x, fmaf(v[k], qv.y, qv.z));
                acc[k] = fmaf(qv.w, fabsf(wv), acc[k]);
            }
        }
#pragma unroll
        for (int k = 0; k < EPT; k++) {
            int p = tid + k * 512;
            if (p < cntE)
                LU[p] = make_float2(fmaf(u[k], la, fmaf(v[k], lb, lc)) + acc[k], u[k]);
        }
        for (int p = tid + 512 * EPT; p < cntE; p += 512) {  // rare overflow
            int2 sd = sl[p];
            float uu = xx[sd.x], vv = xx[sd.y], a2 = 0.f;
            for (int c = 0; c < C_; c++) {
                float4 qv = P[c];
                float wv = fmaf(uu, qv.x, fmaf(vv, qv.y, qv.z));
                a2 = fmaf(qv.w, fabsf(wv), a2);
            }
            LU[p] = make_float2(fmaf(uu, la, fmaf(vv, lb, lc)) + a2, uu);
        }
    };

    auto softmax = [&](int it) {
        if (tid < QN) {
            int a = offsL[tid], b = offsL[tid + 1];
            float m = -INFINITY, den = 0.f, num = 0.f;
            for (int p = a; p < b; ++p) {
                float2 lu = LU[p];
                float nm = fmaxf(m, lu.x);
                float sc = __expf(m - nm);
                float ex = __expf(lu.x - nm);
                den = den * sc + ex;
                num = fmaf(ex, lu.y, num * sc);
                m = nm;
            }
            Sloc[it][tid] = num / den;
        }
    };

    auto writeout = [&](int it) {
        float4* out4 = out + (size_t)((g0 + it) * N_ + lo) * (C_ / 4);
        int node = tid / 24, c4 = tid % 24;
        for (int i = tid; i < QN * (C_ / 4); i += 512) {
            float s = Sloc[it][node];
            float4 wv = wl4[c4], cb = cb4[it][c4];
            out4[i] = make_float4(fmaf(s, wv.x, cb.x), fmaf(s, wv.y, cb.y),
                                  fmaf(s, wv.z, cb.z), fmaf(s, wv.w, cb.w));
            int c4n = c4 + 8;                    // 512 = 21*24 + 8
            int carry = (c4n >= 24) ? 1 : 0;
            node += 21 + carry;
            c4 = c4n - (carry ? 24 : 0);
        }
    };

    logits(0);
    __syncthreads();
    softmax(0);
    __syncthreads();
    writeout(0);          // 96 KB of stores fire...
    logits(1);            // ...and drain underneath this VALU burst
    __syncthreads();
    softmax(1);
    __syncthreads();
    writeout(1);
}

extern "C" void kernel_launch(void* const* d_in, const int* in_sizes, int n_in,
                              void* d_out, int out_size, void* d_ws, size_t ws_size,
                              hipStream_t stream) {
    const float* x    = (const float*)d_in[0];
    const int*   ei   = (const int*)d_in[1];
    const float* Wl   = (const float*)d_in[2];
    const float* bl   = (const float*)d_in[3];
    const float* Wr   = (const float*)d_in[4];
    const float* br   = (const float*)d_in[5];
    const float* att  = (const float*)d_in[6];
    const float* bias = (const float*)d_in[7];
    float4* out = (float4*)d_out;

    char* ws = (char*)d_ws;
    float4* P     = (float4*)(ws + 0);
    float*  lin3g = (float*)(ws + 1536);
    int*    offsG = (int*)(ws + 1552);
    int2*   slots = (int2*)(ws + 5568);

    hipLaunchKernelGGL(kA, dim3(4), dim3(512), 0, stream,
                       ei, Wl, bl, Wr, br, att, P, lin3g, offsG, slots);
    hipLaunchKernelGGL(kF2, dim3(4, G_ / 2), dim3(512), 0, stream,
                       x, P, lin3g, offsG, slots, Wl, bl, bias, out);
}